// Round 7
// baseline (973.520 us; speedup 1.0000x reference)
//
#include <hip/hip_runtime.h>
#include <hip/hip_bf16.h>

typedef __bf16  bf16x8 __attribute__((ext_vector_type(8)));
typedef float   f32x4  __attribute__((ext_vector_type(4)));

__device__ __forceinline__ void wait_vm_n(int n) {   // n vm ops may stay outstanding
  switch (n) {
    case 0:  asm volatile("s_waitcnt vmcnt(0)"  ::: "memory"); break;
    case 2:  asm volatile("s_waitcnt vmcnt(2)"  ::: "memory"); break;
    case 4:  asm volatile("s_waitcnt vmcnt(4)"  ::: "memory"); break;
    case 6:  asm volatile("s_waitcnt vmcnt(6)"  ::: "memory"); break;
    case 8:  asm volatile("s_waitcnt vmcnt(8)"  ::: "memory"); break;
    case 10: asm volatile("s_waitcnt vmcnt(10)" ::: "memory"); break;
    case 12: asm volatile("s_waitcnt vmcnt(12)" ::: "memory"); break;
    case 14: asm volatile("s_waitcnt vmcnt(14)" ::: "memory"); break;
    case 16: asm volatile("s_waitcnt vmcnt(16)" ::: "memory"); break;
    default: asm volatile("s_waitcnt vmcnt(18)" ::: "memory"); break;
  }
}
#define WAIT_VM0 asm volatile("s_waitcnt vmcnt(0)" ::: "memory")

__device__ __forceinline__ float sigm(float x)  { return 1.0f / (1.0f + __expf(-x)); }
__device__ __forceinline__ float tanhp(float x) { return 2.0f / (1.0f + __expf(-2.0f * x)) - 1.0f; }

// direct-to-register 16B global loads. COH: sc0 = bypass L1 (h panels,
// cross-XCD freshness via LLC; same aux as R10's GLOAD16_H). Results are
// valid only after a manual vmcnt wait + sched_barrier (rule #18).
template<bool COH>
__device__ __forceinline__ bf16x8 gl16(const __hip_bfloat16* p) {
  f32x4 v;
  if (COH) asm volatile("global_load_dwordx4 %0, %1, off sc0" : "=v"(v) : "v"(p));
  else     asm volatile("global_load_dwordx4 %0, %1, off"     : "=v"(v) : "v"(p));
  return *(bf16x8*)&v;
}

// LLC-coherent scalar load / stores (bypass L1/L2)
__device__ __forceinline__ unsigned int coh_load(const unsigned int* p) {
  unsigned int v;
  asm volatile("global_load_dword %0, %1, off sc0 sc1\n\ts_waitcnt vmcnt(0)"
               : "=v"(v) : "v"(p) : "memory");
  return v;
}
__device__ __forceinline__ int coh_load_i(const int* p) {
  int v;
  asm volatile("global_load_dword %0, %1, off sc0 sc1\n\ts_waitcnt vmcnt(0)"
               : "=v"(v) : "v"(p) : "memory");
  return v;
}
__device__ __forceinline__ void coh_store16(void* p, bf16x8 v) {
  f32x4 f = *(f32x4*)&v;
  asm volatile("global_store_dwordx4 %0, %1, off sc0 sc1" :: "v"(p), "v"(f) : "memory");
}
__device__ __forceinline__ void flag_store(int* fp, int v) {
  asm volatile("global_store_dword %0, %1, off sc0 sc1" :: "v"(fp), "v"(v) : "memory");
}

#define TSTEPS 80
#define BATCH  512
#define EDIM   256
#define HDIM   512
#define K2     1024
#define K1     768
#define NCH    12           // B K-chunks in registers (192 VGPR; frees 64 for af buffer)
#define ADEPTH 10           // A-chunk register prefetch depth (80 VGPR, ~650ns cover)
#define D_SLOTS 12
#define SLOT_BYTES 524544   // 512 KB + 256 B guard
// LDS: BsL (<=20 chunks * 4KB = 80KB) | epi (128 x 24 bf16)
#define EPI_OFF  81920
#define EPI_STR  24
#define LDS_BYTES 88064

struct Params {
  const __hip_bfloat16* Wz1t;   // [2048][768]  bf16, [N'][K], K-order [W1|U1] (x first)
  const __hip_bfloat16* Wz2t;   // [2048][1024]             K-order [W2|U2] (h1 first)
  const float* bz1;             // [2048] permuted
  const float* bz2;
  const __hip_bfloat16* Xall;   // [80][512][256] bf16
  char* h1base;                 // 12 slots, SLOT_BYTES stride
  char* h2base;                 // 12 slots
  int* flags;                   // 256 entries, 16B stride: z1 at idx, z2 at 128+idx
  const float* Wfc; const float* bfc;
  float* out;
};

// ---------------- prep kernels ----------------
// permuted column: n' = ntile*64 + gate*16 + u  (ntile = j>>4, u = j&15)
// K-order: the TIGHT-gated operand goes LAST:
//   Wz1t: k<256 -> W1[k] (x),  k>=256 -> U1[k-256] (h1[s-1], peer-gated)
//   Wz2t: k<512 -> W2[k] (h1), k>=512 -> U2[k-512] (h2[s-1], peer-gated)

__global__ __launch_bounds__(256) void prep_weights(
    const float* __restrict__ W1, const float* __restrict__ U1, const float* __restrict__ b1,
    const float* __restrict__ W2, const float* __restrict__ U2, const float* __restrict__ b2,
    __hip_bfloat16* __restrict__ Wz1t, __hip_bfloat16* __restrict__ Wz2t,
    float* __restrict__ bz1, float* __restrict__ bz2) {
  long idx = (long)blockIdx.x * 256 + threadIdx.x;
  const long n1 = 2048L * K1, n2 = 2048L * K2;
  if (idx < n1) {
    int n = (int)(idx / K1), k = (int)(idx % K1);
    int col = ((n >> 4) & 3) * 512 + (n >> 6) * 16 + (n & 15);
    float v = (k < 256) ? W1[(size_t)k * 2048 + col] : U1[(size_t)(k - 256) * 2048 + col];
    Wz1t[idx] = __float2bfloat16(v);
  } else if (idx < n1 + n2) {
    long r = idx - n1;
    int n = (int)(r / K2), k = (int)(r % K2);
    int col = ((n >> 4) & 3) * 512 + (n >> 6) * 16 + (n & 15);
    float v = (k < 512) ? W2[(size_t)k * 2048 + col] : U2[(size_t)(k - 512) * 2048 + col];
    Wz2t[r] = __float2bfloat16(v);
  } else if (idx < n1 + n2 + 2048) {
    int n = (int)(idx - (n1 + n2));
    bz1[n] = b1[((n >> 4) & 3) * 512 + (n >> 6) * 16 + (n & 15)];
  } else if (idx < n1 + n2 + 4096) {
    int n = (int)(idx - (n1 + n2 + 2048));
    bz2[n] = b2[((n >> 4) & 3) * 512 + (n >> 6) * 16 + (n & 15)];
  }
}

__global__ __launch_bounds__(256) void prep_gather(
    const int* __restrict__ tokens, const float* __restrict__ emb,
    __hip_bfloat16* __restrict__ Xall, float4* __restrict__ zp, int zn) {
  int idx = blockIdx.x * 256 + threadIdx.x;
  if (idx < zn) zp[idx] = make_float4(0.f, 0.f, 0.f, 0.f);   // zero state+flags
  int e  = (idx & 63) * 4;
  int rb = idx >> 6;            // t*512 + b
  int t  = rb >> 9;
  int b  = rb & 511;
  int tok = tokens[b * TSTEPS + t];
  const float4 v = *(const float4*)&emb[(size_t)tok * EDIM + e];
  __hip_bfloat16* o = Xall + (size_t)rb * EDIM + e;
  o[0] = __float2bfloat16(v.x); o[1] = __float2bfloat16(v.y);
  o[2] = __float2bfloat16(v.z); o[3] = __float2bfloat16(v.w);
}

// ---------------- main kernel ----------------
// R13 = R10's step/gate/tail structure + ONE structural delta: A-panel
// staging goes DIRECT TO REGISTERS (rolling af[ADEPTH][2] buffer, statically
// indexed in the fully-unrolled K-loop) instead of through the LDS ring.
// Why: the A-fragment is wave-local and per-lane-contiguous (16B at
// row=m0+w*32+mi*16+m16, col=kc*32+q*8; a load instruction covers 16 rows x
// 64B fully coalesced), so the LDS round-trip added nothing but latency; and
// the ring capped the prefetch window at ~5 chunks (~325ns) while sc0 LLC
// loads take 600-900ns -> the K-loop was latency-bound at ~2x compute time
// (Little's law; matches MfmaUtil 21%). ADEPTH=10 gives ~650ns cover.
// NCH 16->12 frees the 64 VGPRs for af. B path unchanged (breg + BsL,
// compiler-managed lgkm waits). vmcnt discipline: loads retire in order; at
// chunk kc, allowed outstanding = 2*min(ADEPTH-1, chunks-left); each wait is
// followed by sched_barrier(0) so MFMAs can't hoist past it (rule #18).
// Gates/fences/slot rotation byte-identical to R10 (proven 610us).

__device__ __forceinline__ void gate_wave(const int* flags, int base1, int t1,
                                          int base2, int t2, int lane) {
  const int idx = lane & 31;
  const int* fp = flags + (((lane < 32) ? base1 : base2) + idx) * 4;   // 16B stride
  const int tgt = (lane < 32) ? t1 : t2;
  for (;;) {
    int v = coh_load_i(fp);
    if (__ballot(v >= tgt) == ~0ull) break;
    __builtin_amdgcn_s_sleep(2);
  }
}

template<int K0, int LEN, int STRIDE, bool COH>
__device__ __forceinline__ void run_part(
    const __hip_bfloat16* __restrict__ Asrc, int m0, int w, int lane,
    const __hip_bfloat16* __restrict__ BsL,
    const bf16x8 (&breg)[NCH][4], const int (&boff)[4],
    f32x4 (&acc)[2][4]) {
  const int q = lane >> 4, m16 = lane & 15;
  const __hip_bfloat16* b0 = Asrc + (size_t)(m0 + w * 32 + m16) * STRIDE + q * 8;
  const __hip_bfloat16* b1 = b0 + (size_t)16 * STRIDE;

  bf16x8 af[ADEPTH][2];
  bf16x8 bf[2][4];
  constexpr int F = (ADEPTH < LEN) ? ADEPTH : LEN;
#pragma unroll
  for (int f = 0; f < F; ++f) {                        // fill
    af[f][0] = gl16<COH>(b0 + f * 32);
    af[f][1] = gl16<COH>(b1 + f * 32);
  }
  if (K0 >= NCH) {
#pragma unroll
    for (int g = 0; g < 4; ++g)
      bf[0][g] = *(const bf16x8*)(BsL + (K0 - NCH) * 2048 + boff[g]);
  }

#pragma unroll
  for (int i = 0; i < LEN; ++i) {
    const int kc  = K0 + i;
    const int cur = i & 1, nxt = cur ^ 1;
    // prefetch next chunk's B fragments (compiler inserts the lgkm waits)
    if (i + 1 < LEN && kc + 1 >= NCH) {
#pragma unroll
      for (int g = 0; g < 4; ++g)
        bf[nxt][g] = *(const bf16x8*)(BsL + (kc + 1 - NCH) * 2048 + boff[g]);
    }
    {
      const int rem = LEN - 1 - i;                     // chunks after kc
      wait_vm_n(2 * (ADEPTH - 1 < rem ? ADEPTH - 1 : rem));   // kc resident
      __builtin_amdgcn_sched_barrier(0);
    }
#pragma unroll
    for (int mi = 0; mi < 2; ++mi)
#pragma unroll
      for (int g = 0; g < 4; ++g)
        acc[mi][g] = __builtin_amdgcn_mfma_f32_16x16x32_bf16(
            af[i % ADEPTH][mi], (kc < NCH ? breg[kc][g] : bf[cur][g]), acc[mi][g], 0, 0, 0);
    // refill the slot just consumed with chunk kc+ADEPTH
    if (i + ADEPTH < LEN) {
      af[i % ADEPTH][0] = gl16<COH>(b0 + (i + ADEPTH) * 32);
      af[i % ADEPTH][1] = gl16<COH>(b1 + (i + ADEPTH) * 32);
    }
  }
}

template<bool Z2>
__device__ __forceinline__ void role_loop(const Params& p, char* smem, int tid,
                                          int grp, int ntile) {
  constexpr int K   = Z2 ? K2 : K1;
  constexpr int NC  = K / 32;
  const int lane = tid & 63;
  const int w    = tid >> 6;
  const int q    = lane >> 4;
  const int m16  = lane & 15;
  const int m0   = grp * 128;
  const int n0   = ntile * 64;

  __hip_bfloat16* BsL  = (__hip_bfloat16*)smem;
  __hip_bfloat16* epi  = (__hip_bfloat16*)(smem + EPI_OFF);

  const __hip_bfloat16* Bg = (Z2 ? p.Wz2t : p.Wz1t) + (size_t)n0 * K;

  // one-time: B chunks 0..NCH-1 into registers (static indexing only)
  bf16x8 breg[NCH][4];
#pragma unroll
  for (int kc = 0; kc < NCH; ++kc)
#pragma unroll
    for (int g = 0; g < 4; ++g)
      breg[kc][g] = *(const bf16x8*)(Bg + (size_t)(g * 16 + m16) * K + kc * 32 + q * 8);

  // one-time: B chunks NCH..NC-1 into LDS, chunk-major granule-swizzled
  for (int it0 = tid; it0 < (NC - NCH) * 256; it0 += 256) {
    int cid = it0 >> 8, gg = it0 & 255;
    int r = gg >> 2, c8 = gg & 3;
    int sw = c8 ^ ((r >> 1) & 3);
    *(bf16x8*)(BsL + cid * 2048 + r * 32 + sw * 8) =
        *(const bf16x8*)(Bg + (size_t)r * K + (NCH + cid) * 32 + c8 * 8);
  }
  const float* bias = Z2 ? p.bz2 : p.bz1;
  float bz[4];
#pragma unroll
  for (int g = 0; g < 4; ++g) bz[g] = bias[n0 + g * 16 + m16];

  const int swz = (q ^ ((m16 >> 1) & 3)) * 8;
  int boff[4];
#pragma unroll
  for (int g = 0; g < 4; ++g) boff[g] = (g * 16 + m16) * 32 + swz;

  float cst[2][4] = {{0.f,0.f,0.f,0.f},{0.f,0.f,0.f,0.f}};
  const int fself = (Z2 ? 128 : 0) + grp * 32 + ntile;
  const int jbase = ntile * 16;
  __syncthreads();

  // pre-loop: z2's slack gate for step 0 (z1 >= 1 -> h1[0] committed)
  if (Z2) {
    if (w == 0) gate_wave(p.flags, grp * 32, 1, grp * 32, 1, lane);
    __syncthreads();
  }

  for (int s = 0; s < TSTEPS; ++s) {
    const int sl = s % D_SLOTS, slp = (s + D_SLOTS - 1) % D_SLOTS;
    const __hip_bfloat16* Aa = Z2
        ? (const __hip_bfloat16*)(p.h1base + (size_t)sl * SLOT_BYTES)    // h1[s]
        : p.Xall + (size_t)s * BATCH * EDIM;                             // x[s]
    const __hip_bfloat16* Ab = Z2
        ? (const __hip_bfloat16*)(p.h2base + (size_t)slp * SLOT_BYTES)   // h2[s-1]
        : (const __hip_bfloat16*)(p.h1base + (size_t)slp * SLOT_BYTES);  // h1[s-1]
    __hip_bfloat16* hout = (__hip_bfloat16*)
        ((Z2 ? p.h2base : p.h1base) + (size_t)sl * SLOT_BYTES);

    f32x4 acc[2][4];
#pragma unroll
    for (int mi = 0; mi < 2; ++mi)
#pragma unroll
      for (int g = 0; g < 4; ++g)
        acc[mi][g] = (f32x4){bz[g], bz[g], bz[g], bz[g]};

    // ---- part A (z2 slack gate already satisfied in previous tail) ----
    if (Z2) run_part<0, 16, 512, true >(Aa, m0, w, lane, BsL, breg, boff, acc);
    else    run_part<0,  8, 256, false>(Aa, m0, w, lane, BsL, breg, boff, acc);

    // ---- part B gate (tight peer RAW, hidden behind part A) + fence ----
    if (w == 0) {
      if (Z2) gate_wave(p.flags, 128 + grp * 32, s, 128 + grp * 32, s, lane);
      else    gate_wave(p.flags, grp * 32, s, 128 + grp * 32, s - (D_SLOTS - 1), lane);
      if ((s & 7) == 0) __builtin_amdgcn_fence(__ATOMIC_ACQUIRE, "agent");
    }
    __syncthreads();
    if (Z2) run_part<16, 16, 512, true>(Ab, m0, w, lane, BsL, breg, boff, acc);
    else    run_part< 8, 16, 512, true>(Ab, m0, w, lane, BsL, breg, boff, acc);

    // epilogue: gates -> cell state (regs) -> h via LDS transpose
#pragma unroll
    for (int mi = 0; mi < 2; ++mi)
#pragma unroll
      for (int rr = 0; rr < 4; ++rr) {
        const float zi = acc[mi][0][rr], zf = acc[mi][1][rr];
        const float zg = acc[mi][2][rr], zo = acc[mi][3][rr];
        const float cn = sigm(zf) * cst[mi][rr] + sigm(zi) * tanhp(zg);
        cst[mi][rr] = cn;
        epi[(w * 32 + mi * 16 + q * 4 + rr) * EPI_STR + m16] = __float2bfloat16(sigm(zo) * tanhp(cn));
      }
    __syncthreads();
    {
      const int r = tid >> 1, hf = tid & 1;
      bf16x8 hv = *(const bf16x8*)(epi + r * EPI_STR + hf * 8);
      coh_store16(hout + (size_t)(m0 + r) * HDIM + jbase + hf * 8, hv);
    }
    // z2: next step's slack gate polls here -- its vmcnt(0) subsumes the
    // store drain, so flag_store is not delayed. (z1 lead >= 2 in steady
    // state; startup transient only at s=0.)
    if (Z2 && w == 0 && s + 1 < TSTEPS)
      gate_wave(p.flags, grp * 32, s + 2, grp * 32, s + 2, lane);
    WAIT_VM0;                                      // h committed to LLC
    __syncthreads();
    if (tid == 0) flag_store(p.flags + fself * 4, s + 1);
  }
}

__global__ __launch_bounds__(256, 1) void lstm_seq(Params p) {
  extern __shared__ char smem[];
  const int tid = threadIdx.x;
  const bool z2  = ((blockIdx.x & 1) == 0);
  const int grp  = (blockIdx.x >> 1) & 3;
  const int ntile = blockIdx.x >> 3;

  if (z2) role_loop<true>(p, smem, tid, grp, ntile);
  else    role_loop<false>(p, smem, tid, grp, ntile);

  // final FC: block b -> rows {2b, 2b+1}; wait on producing z2 group's flags
  const int lane = tid & 63, w = tid >> 6;
  if (w == 0) {
    const int g2 = blockIdx.x >> 6;
    gate_wave(p.flags, 128 + g2 * 32, TSTEPS, 128 + g2 * 32, TSTEPS, lane);
  }
  __syncthreads();
  if (w < 2) {
    const int row = blockIdx.x * 2 + w;
    const unsigned int* hp = (const unsigned int*)
        (p.h2base + (size_t)((TSTEPS - 1) % D_SLOTS) * SLOT_BYTES) + (size_t)row * (HDIM / 2);
    float sum = 0.f;
#pragma unroll
    for (int cc = 0; cc < 4; ++cc) {
      unsigned int d = coh_load(hp + lane * 4 + cc);
      union { unsigned int ui; float f; } lo, hi;
      lo.ui = d << 16; hi.ui = d & 0xffff0000u;
      sum += lo.f * p.Wfc[(lane * 4 + cc) * 2] + hi.f * p.Wfc[(lane * 4 + cc) * 2 + 1];
    }
#pragma unroll
    for (int o = 32; o > 0; o >>= 1) sum += __shfl_down(sum, o, 64);
    if (lane == 0) p.out[row] = sigm(sum + p.bfc[0]);
  }
}

// ---------------- host launcher ----------------

extern "C" void kernel_launch(void* const* d_in, const int* in_sizes, int n_in,
                              void* d_out, int out_size, void* d_ws, size_t ws_size,
                              hipStream_t stream) {
  const int*   tokens = (const int*)d_in[0];
  const float* emb = (const float*)d_in[1];
  const float* W1  = (const float*)d_in[2];
  const float* U1  = (const float*)d_in[3];
  const float* b1  = (const float*)d_in[4];
  const float* W2  = (const float*)d_in[5];
  const float* U2  = (const float*)d_in[6];
  const float* b2  = (const float*)d_in[7];
  const float* Wfc = (const float*)d_in[8];
  const float* bfc = (const float*)d_in[9];

  char* ws = (char*)d_ws;
  size_t off = 0;
  auto alloc = [&](size_t bytes) {
    char* r = ws + off;
    off += (bytes + 255) & ~(size_t)255;
    return r;
  };
  __hip_bfloat16* Wz1t = (__hip_bfloat16*)alloc(2048UL * K1 * 2);
  __hip_bfloat16* Wz2t = (__hip_bfloat16*)alloc(2048UL * K2 * 2);
  float* bz1 = (float*)alloc(2048 * 4);
  float* bz2 = (float*)alloc(2048 * 4);
  __hip_bfloat16* Xall = (__hip_bfloat16*)alloc((size_t)TSTEPS * BATCH * EDIM * 2);
  // state: 24 h-slots (12 h1 + 12 h2) + flags (4096B), ALL zeroed in prep_gather
  const size_t state_bytes = 24UL * SLOT_BYTES + 4096;   // 12,593,152
  char* state = alloc(state_bytes);

  Params prm;
  prm.h1base = state;
  prm.h2base = state + 12UL * SLOT_BYTES;
  prm.flags  = (int*)(state + 24UL * SLOT_BYTES);

  prep_weights<<<dim3(14352), dim3(256), 0, stream>>>(W1, U1, b1, W2, U2, b2, Wz1t, Wz2t, bz1, bz2);
  prep_gather<<<dim3(10240), dim3(256), 0, stream>>>(tokens, emb, Xall,
                                                     (float4*)state, (int)(state_bytes / 16));

  hipFuncSetAttribute((const void*)lstm_seq,
                      hipFuncAttributeMaxDynamicSharedMemorySize, LDS_BYTES);

  prm.Wz1t = Wz1t; prm.Wz2t = Wz2t; prm.bz1 = bz1; prm.bz2 = bz2;
  prm.Xall = Xall;
  prm.Wfc = Wfc; prm.bfc = bfc;
  prm.out = (float*)d_out;

  lstm_seq<<<dim3(256), dim3(256), LDS_BYTES, stream>>>(prm);
}

// Round 8
// 704.976 us; speedup vs baseline: 1.3809x; 1.3809x over previous
//
#include <hip/hip_runtime.h>
#include <hip/hip_bf16.h>

typedef __bf16  bf16x8 __attribute__((ext_vector_type(8)));
typedef float   f32x4  __attribute__((ext_vector_type(4)));

// global->LDS async, 16B/lane. _C: fully cached (immutable X stream).
// _H: sc0 = bypass L1, allocate L2 (h panels; freshness via 12-deep slot
// rotation + aligned fence every 8 phases -- proven R7).
#define GLOAD16_C(gptr, lptr) \
  __builtin_amdgcn_global_load_lds((const __attribute__((address_space(1))) void*)(gptr), \
                                   (__attribute__((address_space(3))) void*)(lptr), 16, 0, 0)
#define GLOAD16_H(gptr, lptr) \
  __builtin_amdgcn_global_load_lds((const __attribute__((address_space(1))) void*)(gptr), \
                                   (__attribute__((address_space(3))) void*)(lptr), 16, 0, 0x1)

__device__ __forceinline__ void wait_vm_chunks(int n) {   // n chunks (2 vm each) may stay outstanding
  switch (n) {
    case 0:  asm volatile("s_waitcnt vmcnt(0)"  ::: "memory"); break;
    case 1:  asm volatile("s_waitcnt vmcnt(2)"  ::: "memory"); break;
    case 2:  asm volatile("s_waitcnt vmcnt(4)"  ::: "memory"); break;
    case 3:  asm volatile("s_waitcnt vmcnt(6)"  ::: "memory"); break;
    case 4:  asm volatile("s_waitcnt vmcnt(8)"  ::: "memory"); break;
    case 5:  asm volatile("s_waitcnt vmcnt(10)" ::: "memory"); break;
    case 6:  asm volatile("s_waitcnt vmcnt(12)" ::: "memory"); break;
    case 7:  asm volatile("s_waitcnt vmcnt(14)" ::: "memory"); break;
    default: asm volatile("s_waitcnt vmcnt(16)" ::: "memory"); break;
  }
}
#define WAIT_VM0 asm volatile("s_waitcnt vmcnt(0)" ::: "memory")

__device__ __forceinline__ void wait_lgkm_n(int n) {
  if      (n <= 0) asm volatile("s_waitcnt lgkmcnt(0)" ::: "memory");
  else if (n <= 2) asm volatile("s_waitcnt lgkmcnt(2)" ::: "memory");
  else             asm volatile("s_waitcnt lgkmcnt(6)" ::: "memory");
}

__device__ __forceinline__ float sigm(float x)  { return 1.0f / (1.0f + __expf(-x)); }
__device__ __forceinline__ float tanhp(float x) { return 2.0f / (1.0f + __expf(-2.0f * x)) - 1.0f; }

// LLC-coherent scalar load / stores (bypass L1/L2)
__device__ __forceinline__ unsigned int coh_load(const unsigned int* p) {
  unsigned int v;
  asm volatile("global_load_dword %0, %1, off sc0 sc1\n\ts_waitcnt vmcnt(0)"
               : "=v"(v) : "v"(p) : "memory");
  return v;
}
__device__ __forceinline__ int coh_load_i(const int* p) {
  int v;
  asm volatile("global_load_dword %0, %1, off sc0 sc1\n\ts_waitcnt vmcnt(0)"
               : "=v"(v) : "v"(p) : "memory");
  return v;
}
__device__ __forceinline__ void coh_store16(void* p, bf16x8 v) {
  f32x4 f = *(f32x4*)&v;
  asm volatile("global_store_dwordx4 %0, %1, off sc0 sc1" :: "v"(p), "v"(f) : "memory");
}
__device__ __forceinline__ void flag_store(int* fp, int v) {
  asm volatile("global_store_dword %0, %1, off sc0 sc1" :: "v"(fp), "v"(v) : "memory");
}

#define TSTEPS 80
#define BATCH  512
#define EDIM   256
#define HDIM   512
#define K2     1024
#define K1     768
#define NCH    16           // B K-chunks in registers
#define RS     10           // ring slots (was 8): lookahead 9, 7 chunks outstanding
#define D_SLOTS 12
#define SLOT_BYTES 524544   // 512 KB + 256 B guard
// LDS: BsL (16 chunks * 4KB = 64KB) | ring (10 * 8KB = 80KB) | epi (128 x 24 bf16)
#define RING_OFF 65536
#define EPI_OFF  147456
#define EPI_STR  24
#define LDS_BYTES 153600

struct Params {
  const __hip_bfloat16* Wz1t;   // [2048][768]  bf16, [N'][K], K-order [W1|U1] (x first)
  const __hip_bfloat16* Wz2t;   // [2048][1024]             K-order [W2|U2] (h1 first)
  const float* bz1;             // [2048] permuted
  const float* bz2;
  const __hip_bfloat16* Xall;   // [80][512][256] bf16
  char* h1base;                 // 12 slots, SLOT_BYTES stride
  char* h2base;                 // 12 slots
  int* flags;                   // 256 entries, 16B stride: z1 at idx, z2 at 128+idx
  const float* Wfc; const float* bfc;
  float* out;
};

// ---------------- prep kernels ----------------
// permuted column: n' = ntile*64 + gate*16 + u  (ntile = j>>4, u = j&15)
// K-order: the TIGHT-gated operand goes LAST:
//   Wz1t: k<256 -> W1[k] (x),  k>=256 -> U1[k-256] (h1[s-1], peer-gated)
//   Wz2t: k<512 -> W2[k] (h1), k>=512 -> U2[k-512] (h2[s-1], peer-gated)

__global__ __launch_bounds__(256) void prep_weights(
    const float* __restrict__ W1, const float* __restrict__ U1, const float* __restrict__ b1,
    const float* __restrict__ W2, const float* __restrict__ U2, const float* __restrict__ b2,
    __hip_bfloat16* __restrict__ Wz1t, __hip_bfloat16* __restrict__ Wz2t,
    float* __restrict__ bz1, float* __restrict__ bz2) {
  long idx = (long)blockIdx.x * 256 + threadIdx.x;
  const long n1 = 2048L * K1, n2 = 2048L * K2;
  if (idx < n1) {
    int n = (int)(idx / K1), k = (int)(idx % K1);
    int col = ((n >> 4) & 3) * 512 + (n >> 6) * 16 + (n & 15);
    float v = (k < 256) ? W1[(size_t)k * 2048 + col] : U1[(size_t)(k - 256) * 2048 + col];
    Wz1t[idx] = __float2bfloat16(v);
  } else if (idx < n1 + n2) {
    long r = idx - n1;
    int n = (int)(r / K2), k = (int)(r % K2);
    int col = ((n >> 4) & 3) * 512 + (n >> 6) * 16 + (n & 15);
    float v = (k < 512) ? W2[(size_t)k * 2048 + col] : U2[(size_t)(k - 512) * 2048 + col];
    Wz2t[r] = __float2bfloat16(v);
  } else if (idx < n1 + n2 + 2048) {
    int n = (int)(idx - (n1 + n2));
    bz1[n] = b1[((n >> 4) & 3) * 512 + (n >> 6) * 16 + (n & 15)];
  } else if (idx < n1 + n2 + 4096) {
    int n = (int)(idx - (n1 + n2 + 2048));
    bz2[n] = b2[((n >> 4) & 3) * 512 + (n >> 6) * 16 + (n & 15)];
  }
}

__global__ __launch_bounds__(256) void prep_gather(
    const int* __restrict__ tokens, const float* __restrict__ emb,
    __hip_bfloat16* __restrict__ Xall, float4* __restrict__ zp, int zn) {
  int idx = blockIdx.x * 256 + threadIdx.x;
  if (idx < zn) zp[idx] = make_float4(0.f, 0.f, 0.f, 0.f);   // zero state+flags
  int e  = (idx & 63) * 4;
  int rb = idx >> 6;            // t*512 + b
  int t  = rb >> 9;
  int b  = rb & 511;
  int tok = tokens[b * TSTEPS + t];
  const float4 v = *(const float4*)&emb[(size_t)tok * EDIM + e];
  __hip_bfloat16* o = Xall + (size_t)rb * EDIM + e;
  o[0] = __float2bfloat16(v.x); o[1] = __float2bfloat16(v.y);
  o[2] = __float2bfloat16(v.z); o[3] = __float2bfloat16(v.w);
}

// ---------------- main kernel ----------------
// R14 = R10 (proven 610us; gates/tail/fences byte-identical) + ONE delta:
// the LDS staging ring grows 8 -> 10 slots (LDS 137 -> 150KB), lookahead
// 6 -> 9, steady-state allowed-outstanding 4 -> 7 chunks. Why: the K-loop is
// latency-bound -- per-chunk compute is 8 MFMA ~ 155cyc but sc0/LLC staging
// latency is ~600-900cyc and the old window covered only ~620cyc (Little's
// law -> staging serviced slower than compute, matching MfmaUtil 21%). The
// new window covers ~1085cyc. R13 proved reg-staging is NOT the fix (m151
// replicated: VGPR-return path serializes vs MFMA; 884us). Slot safety at
// stage(kc+9) -> slot (kc-1)%10: that chunk's ds_reads (issued iter i-2)
// retired by the FIFO lgkm discipline (<=6 outstanding at each wait). All
// ring indices compile-time (%10 free in unrolled code).

__device__ __forceinline__ void gate_wave(const int* flags, int base1, int t1,
                                          int base2, int t2, int lane) {
  const int idx = lane & 31;
  const int* fp = flags + (((lane < 32) ? base1 : base2) + idx) * 4;   // 16B stride
  const int tgt = (lane < 32) ? t1 : t2;
  for (;;) {
    int v = coh_load_i(fp);
    if (__ballot(v >= tgt) == ~0ull) break;
    __builtin_amdgcn_s_sleep(2);
  }
}

template<int K0, int LEN, int STRIDE, bool COH>
__device__ __forceinline__ void run_part(
    const __hip_bfloat16* __restrict__ Asrc, int m0, int w, int lane,
    __hip_bfloat16* __restrict__ ring, const __hip_bfloat16* __restrict__ BsL,
    const bf16x8 (&breg)[NCH][4], const int (&aoff)[2], const int (&boff)[4],
    f32x4 (&acc)[2][4]) {
  constexpr int FILL = (LEN < 9) ? LEN : 9;           // lookahead depth
  auto stage = [&](int kc) {
#pragma unroll
    for (int it = 0; it < 2; ++it) {
      const int gbase = w * 128 + it * 64;
      const int g   = gbase + lane;
      const int row = g >> 2;
      const int gc  = (g & 3) ^ ((row >> 1) & 3);       // XOR swizzle
      __hip_bfloat16* lp = ring + (kc % RS) * 4096 + gbase * 8;
      const __hip_bfloat16* gp = Asrc + (size_t)(m0 + row) * STRIDE + (kc - K0) * 32 + gc * 8;
      if (COH) GLOAD16_H(gp, lp); else GLOAD16_C(gp, lp);
    }
  };
#pragma unroll
  for (int f = 0; f < FILL; ++f) stage(K0 + f);

  bf16x8 af[2][2], bf[2][4];
  wait_vm_chunks(FILL - 1);                             // chunk K0 resident
#pragma unroll
  for (int mi = 0; mi < 2; ++mi)
    af[0][mi] = *(const bf16x8*)(ring + (K0 % RS) * 4096 + aoff[mi]);
  if (K0 >= NCH)
#pragma unroll
    for (int g = 0; g < 4; ++g)
      bf[0][g] = *(const bf16x8*)(BsL + (K0 - NCH) * 2048 + boff[g]);

#pragma unroll
  for (int i = 0; i < LEN; ++i) {
    const int kc  = K0 + i;
    const int cur = i & 1, nxt = cur ^ 1;
    if (i + 1 < LEN) {
      wait_vm_chunks(LEN - 2 - i < FILL - 2 ? LEN - 2 - i : FILL - 2);  // kc+1 resident
      const int kn = kc + 1;
#pragma unroll
      for (int mi = 0; mi < 2; ++mi)
        af[nxt][mi] = *(const bf16x8*)(ring + (kn % RS) * 4096 + aoff[mi]);
      if (kn >= NCH) {
#pragma unroll
        for (int g = 0; g < 4; ++g)
          bf[nxt][g] = *(const bf16x8*)(BsL + (kn - NCH) * 2048 + boff[g]);
        wait_lgkm_n(6);                 // frags of kc done; kc+1's 6 in flight
      } else {
        wait_lgkm_n(2);
      }
      if (i + FILL < LEN) stage(kc + FILL);  // slot (kc-1)%RS: reads retired
    } else {
      wait_lgkm_n(0);
    }
#pragma unroll
    for (int mi = 0; mi < 2; ++mi)
#pragma unroll
      for (int g = 0; g < 4; ++g)
        acc[mi][g] = __builtin_amdgcn_mfma_f32_16x16x32_bf16(
            af[cur][mi], (kc < NCH ? breg[kc][g] : bf[cur][g]), acc[mi][g], 0, 0, 0);
  }
}

template<bool Z2>
__device__ __forceinline__ void role_loop(const Params& p, char* smem, int tid,
                                          int grp, int ntile) {
  constexpr int K   = Z2 ? K2 : K1;
  constexpr int NC  = K / 32;
  const int lane = tid & 63;
  const int w    = tid >> 6;
  const int q    = lane >> 4;
  const int m16  = lane & 15;
  const int m0   = grp * 128;
  const int n0   = ntile * 64;

  __hip_bfloat16* BsL  = (__hip_bfloat16*)smem;
  __hip_bfloat16* ring = (__hip_bfloat16*)(smem + RING_OFF);
  __hip_bfloat16* epi  = (__hip_bfloat16*)(smem + EPI_OFF);

  const __hip_bfloat16* Bg = (Z2 ? p.Wz2t : p.Wz1t) + (size_t)n0 * K;

  // one-time: B chunks 0..NCH-1 into registers (static indexing only)
  bf16x8 breg[NCH][4];
#pragma unroll
  for (int kc = 0; kc < NCH; ++kc)
#pragma unroll
    for (int g = 0; g < 4; ++g)
      breg[kc][g] = *(const bf16x8*)(Bg + (size_t)(g * 16 + m16) * K + kc * 32 + q * 8);

  // one-time: B chunks NCH..NC-1 into LDS, chunk-major granule-swizzled
  for (int it0 = tid; it0 < (NC - NCH) * 256; it0 += 256) {
    int cid = it0 >> 8, gg = it0 & 255;
    int r = gg >> 2, c8 = gg & 3;
    int sw = c8 ^ ((r >> 1) & 3);
    *(bf16x8*)(BsL + cid * 2048 + r * 32 + sw * 8) =
        *(const bf16x8*)(Bg + (size_t)r * K + (NCH + cid) * 32 + c8 * 8);
  }
  const float* bias = Z2 ? p.bz2 : p.bz1;
  float bz[4];
#pragma unroll
  for (int g = 0; g < 4; ++g) bz[g] = bias[n0 + g * 16 + m16];

  const int swz = (q ^ ((m16 >> 1) & 3)) * 8;
  int aoff[2], boff[4];
#pragma unroll
  for (int mi = 0; mi < 2; ++mi) aoff[mi] = (w * 32 + mi * 16 + m16) * 32 + swz;
#pragma unroll
  for (int g = 0; g < 4; ++g)    boff[g]  = (g * 16 + m16) * 32 + swz;

  float cst[2][4] = {{0.f,0.f,0.f,0.f},{0.f,0.f,0.f,0.f}};
  const int fself = (Z2 ? 128 : 0) + grp * 32 + ntile;
  const int jbase = ntile * 16;
  __syncthreads();

  // pre-loop: z2's slack gate for step 0 (z1 >= 1 -> h1[0] committed)
  if (Z2) {
    if (w == 0) gate_wave(p.flags, grp * 32, 1, grp * 32, 1, lane);
    __syncthreads();
  }

  for (int s = 0; s < TSTEPS; ++s) {
    const int sl = s % D_SLOTS, slp = (s + D_SLOTS - 1) % D_SLOTS;
    const __hip_bfloat16* Aa = Z2
        ? (const __hip_bfloat16*)(p.h1base + (size_t)sl * SLOT_BYTES)    // h1[s]
        : p.Xall + (size_t)s * BATCH * EDIM;                             // x[s]
    const __hip_bfloat16* Ab = Z2
        ? (const __hip_bfloat16*)(p.h2base + (size_t)slp * SLOT_BYTES)   // h2[s-1]
        : (const __hip_bfloat16*)(p.h1base + (size_t)slp * SLOT_BYTES);  // h1[s-1]
    __hip_bfloat16* hout = (__hip_bfloat16*)
        ((Z2 ? p.h2base : p.h1base) + (size_t)sl * SLOT_BYTES);

    f32x4 acc[2][4];
#pragma unroll
    for (int mi = 0; mi < 2; ++mi)
#pragma unroll
      for (int g = 0; g < 4; ++g)
        acc[mi][g] = (f32x4){bz[g], bz[g], bz[g], bz[g]};

    // ---- part A (z2 slack gate already satisfied in previous tail) ----
    if (Z2) run_part<0, 16, 512, true >(Aa, m0, w, lane, ring, BsL, breg, aoff, boff, acc);
    else    run_part<0,  8, 256, false>(Aa, m0, w, lane, ring, BsL, breg, aoff, boff, acc);

    // ---- part B gate (tight peer RAW, hidden behind part A) + fence ----
    if (w == 0) {
      if (Z2) gate_wave(p.flags, 128 + grp * 32, s, 128 + grp * 32, s, lane);
      else    gate_wave(p.flags, grp * 32, s, 128 + grp * 32, s - (D_SLOTS - 1), lane);
      if ((s & 7) == 0) __builtin_amdgcn_fence(__ATOMIC_ACQUIRE, "agent");
    }
    __syncthreads();
    if (Z2) run_part<16, 16, 512, true>(Ab, m0, w, lane, ring, BsL, breg, aoff, boff, acc);
    else    run_part< 8, 16, 512, true>(Ab, m0, w, lane, ring, BsL, breg, aoff, boff, acc);

    // epilogue: gates -> cell state (regs) -> h via LDS transpose
#pragma unroll
    for (int mi = 0; mi < 2; ++mi)
#pragma unroll
      for (int rr = 0; rr < 4; ++rr) {
        const float zi = acc[mi][0][rr], zf = acc[mi][1][rr];
        const float zg = acc[mi][2][rr], zo = acc[mi][3][rr];
        const float cn = sigm(zf) * cst[mi][rr] + sigm(zi) * tanhp(zg);
        cst[mi][rr] = cn;
        epi[(w * 32 + mi * 16 + q * 4 + rr) * EPI_STR + m16] = __float2bfloat16(sigm(zo) * tanhp(cn));
      }
    __syncthreads();
    {
      const int r = tid >> 1, hf = tid & 1;
      bf16x8 hv = *(const bf16x8*)(epi + r * EPI_STR + hf * 8);
      coh_store16(hout + (size_t)(m0 + r) * HDIM + jbase + hf * 8, hv);
    }
    // z2: next step's slack gate polls here -- its vmcnt(0) subsumes the
    // store drain, so flag_store is not delayed. (z1 lead >= 2 in steady
    // state; startup transient only at s=0.)
    if (Z2 && w == 0 && s + 1 < TSTEPS)
      gate_wave(p.flags, grp * 32, s + 2, grp * 32, s + 2, lane);
    WAIT_VM0;                                      // h committed to LLC
    __syncthreads();
    if (tid == 0) flag_store(p.flags + fself * 4, s + 1);
  }
}

__global__ __launch_bounds__(256, 1) void lstm_seq(Params p) {
  extern __shared__ char smem[];
  const int tid = threadIdx.x;
  const bool z2  = ((blockIdx.x & 1) == 0);
  const int grp  = (blockIdx.x >> 1) & 3;
  const int ntile = blockIdx.x >> 3;

  if (z2) role_loop<true>(p, smem, tid, grp, ntile);
  else    role_loop<false>(p, smem, tid, grp, ntile);

  // final FC: block b -> rows {2b, 2b+1}; wait on producing z2 group's flags
  const int lane = tid & 63, w = tid >> 6;
  if (w == 0) {
    const int g2 = blockIdx.x >> 6;
    gate_wave(p.flags, 128 + g2 * 32, TSTEPS, 128 + g2 * 32, TSTEPS, lane);
  }
  __syncthreads();
  if (w < 2) {
    const int row = blockIdx.x * 2 + w;
    const unsigned int* hp = (const unsigned int*)
        (p.h2base + (size_t)((TSTEPS - 1) % D_SLOTS) * SLOT_BYTES) + (size_t)row * (HDIM / 2);
    float sum = 0.f;
#pragma unroll
    for (int cc = 0; cc < 4; ++cc) {
      unsigned int d = coh_load(hp + lane * 4 + cc);
      union { unsigned int ui; float f; } lo, hi;
      lo.ui = d << 16; hi.ui = d & 0xffff0000u;
      sum += lo.f * p.Wfc[(lane * 4 + cc) * 2] + hi.f * p.Wfc[(lane * 4 + cc) * 2 + 1];
    }
#pragma unroll
    for (int o = 32; o > 0; o >>= 1) sum += __shfl_down(sum, o, 64);
    if (lane == 0) p.out[row] = sigm(sum + p.bfc[0]);
  }
}

// ---------------- host launcher ----------------

extern "C" void kernel_launch(void* const* d_in, const int* in_sizes, int n_in,
                              void* d_out, int out_size, void* d_ws, size_t ws_size,
                              hipStream_t stream) {
  const int*   tokens = (const int*)d_in[0];
  const float* emb = (const float*)d_in[1];
  const float* W1  = (const float*)d_in[2];
  const float* U1  = (const float*)d_in[3];
  const float* b1  = (const float*)d_in[4];
  const float* W2  = (const float*)d_in[5];
  const float* U2  = (const float*)d_in[6];
  const float* b2  = (const float*)d_in[7];
  const float* Wfc = (const float*)d_in[8];
  const float* bfc = (const float*)d_in[9];

  char* ws = (char*)d_ws;
  size_t off = 0;
  auto alloc = [&](size_t bytes) {
    char* r = ws + off;
    off += (bytes + 255) & ~(size_t)255;
    return r;
  };
  __hip_bfloat16* Wz1t = (__hip_bfloat16*)alloc(2048UL * K1 * 2);
  __hip_bfloat16* Wz2t = (__hip_bfloat16*)alloc(2048UL * K2 * 2);
  float* bz1 = (float*)alloc(2048 * 4);
  float* bz2 = (float*)alloc(2048 * 4);
  __hip_bfloat16* Xall = (__hip_bfloat16*)alloc((size_t)TSTEPS * BATCH * EDIM * 2);
  // state: 24 h-slots (12 h1 + 12 h2) + flags (4096B), ALL zeroed in prep_gather
  const size_t state_bytes = 24UL * SLOT_BYTES + 4096;   // 12,593,152
  char* state = alloc(state_bytes);

  Params prm;
  prm.h1base = state;
  prm.h2base = state + 12UL * SLOT_BYTES;
  prm.flags  = (int*)(state + 24UL * SLOT_BYTES);

  prep_weights<<<dim3(14352), dim3(256), 0, stream>>>(W1, U1, b1, W2, U2, b2, Wz1t, Wz2t, bz1, bz2);
  prep_gather<<<dim3(10240), dim3(256), 0, stream>>>(tokens, emb, Xall,
                                                     (float4*)state, (int)(state_bytes / 16));

  hipFuncSetAttribute((const void*)lstm_seq,
                      hipFuncAttributeMaxDynamicSharedMemorySize, LDS_BYTES);

  prm.Wz1t = Wz1t; prm.Wz2t = Wz2t; prm.bz1 = bz1; prm.bz2 = bz2;
  prm.Xall = Xall;
  prm.Wfc = Wfc; prm.bfc = bfc;
  prm.out = (float*)d_out;

  lstm_seq<<<dim3(256), dim3(256), LDS_BYTES, stream>>>(prm);
}

// Round 9
// 703.682 us; speedup vs baseline: 1.3835x; 1.0018x over previous
//
#include <hip/hip_runtime.h>
#include <hip/hip_bf16.h>

typedef __bf16  bf16x8 __attribute__((ext_vector_type(8)));
typedef float   f32x4  __attribute__((ext_vector_type(4)));

// global->LDS async, 16B/lane. _C: fully cached (immutable X stream).
// _H: sc0 = bypass L1, allocate L2 (h panels; freshness via 12-deep slot
// rotation + aligned fence every 8 phases -- proven R7).
#define GLOAD16_C(gptr, lptr) \
  __builtin_amdgcn_global_load_lds((const __attribute__((address_space(1))) void*)(gptr), \
                                   (__attribute__((address_space(3))) void*)(lptr), 16, 0, 0)
#define GLOAD16_H(gptr, lptr) \
  __builtin_amdgcn_global_load_lds((const __attribute__((address_space(1))) void*)(gptr), \
                                   (__attribute__((address_space(3))) void*)(lptr), 16, 0, 0x1)

#define WAIT_VM10  asm volatile("s_waitcnt vmcnt(10)" ::: "memory")
#define WAIT_VM8   asm volatile("s_waitcnt vmcnt(8)"  ::: "memory")
#define WAIT_VM6   asm volatile("s_waitcnt vmcnt(6)"  ::: "memory")
#define WAIT_VM4   asm volatile("s_waitcnt vmcnt(4)"  ::: "memory")
#define WAIT_VM2   asm volatile("s_waitcnt vmcnt(2)"  ::: "memory")
#define WAIT_VM0   asm volatile("s_waitcnt vmcnt(0)"  ::: "memory")

__device__ __forceinline__ void wait_vm_chunks(int n) {   // n chunks (2 vm each) may stay outstanding
  if      (n <= 0) WAIT_VM0;
  else if (n == 1) WAIT_VM2;
  else if (n == 2) WAIT_VM4;
  else if (n == 3) WAIT_VM6;
  else if (n == 4) WAIT_VM8;
  else             WAIT_VM10;
}
__device__ __forceinline__ void wait_lgkm_n(int n) {
  if      (n <= 0) asm volatile("s_waitcnt lgkmcnt(0)" ::: "memory");
  else if (n <= 2) asm volatile("s_waitcnt lgkmcnt(2)" ::: "memory");
  else             asm volatile("s_waitcnt lgkmcnt(6)" ::: "memory");
}

__device__ __forceinline__ float sigm(float x)  { return 1.0f / (1.0f + __expf(-x)); }
__device__ __forceinline__ float tanhp(float x) { return 2.0f / (1.0f + __expf(-2.0f * x)) - 1.0f; }

// LLC-coherent scalar load / stores (bypass L1/L2)
__device__ __forceinline__ unsigned int coh_load(const unsigned int* p) {
  unsigned int v;
  asm volatile("global_load_dword %0, %1, off sc0 sc1\n\ts_waitcnt vmcnt(0)"
               : "=v"(v) : "v"(p) : "memory");
  return v;
}
__device__ __forceinline__ int coh_load_i(const int* p) {
  int v;
  asm volatile("global_load_dword %0, %1, off sc0 sc1\n\ts_waitcnt vmcnt(0)"
               : "=v"(v) : "v"(p) : "memory");
  return v;
}
__device__ __forceinline__ void coh_store16(void* p, bf16x8 v) {
  f32x4 f = *(f32x4*)&v;
  asm volatile("global_store_dwordx4 %0, %1, off sc0 sc1" :: "v"(p), "v"(f) : "memory");
}
__device__ __forceinline__ void flag_store(int* fp, int v) {
  asm volatile("global_store_dword %0, %1, off sc0 sc1" :: "v"(fp), "v"(v) : "memory");
}

#define TSTEPS 80
#define BATCH  512
#define EDIM   256
#define HDIM   512
#define K2     1024
#define K1     768
#define NCH    20           // B K-chunks in registers/AGPRs (R15: 16->20; breg 320 regs,
                            // total est ~435 < 450 no-spill line; cuts BsL re-reads
                            // 4 chunks * 16KB = 64KB/step/CU per role)
#define D_SLOTS 12
#define SLOT_BYTES 524544   // 512 KB + 256 B guard
// LDS: BsL (<=12 chunks * 4KB = 48KB) | ring (8 * 8KB = 64KB) | epi (128 x 24 bf16)
#define RING_OFF 65536
#define EPI_OFF  131072
#define EPI_STR  24
#define LDS_BYTES 137216

struct Params {
  const __hip_bfloat16* Wz1t;   // [2048][768]  bf16, [N'][K], K-order [W1|U1] (x first)
  const __hip_bfloat16* Wz2t;   // [2048][1024]             K-order [W2|U2] (h1 first)
  const float* bz1;             // [2048] permuted
  const float* bz2;
  const __hip_bfloat16* Xall;   // [80][512][256] bf16
  char* h1base;                 // 12 slots, SLOT_BYTES stride
  char* h2base;                 // 12 slots
  int* flags;                   // 256 entries, 16B stride: z1 at idx, z2 at 128+idx
  const float* Wfc; const float* bfc;
  float* out;
};

// ---------------- prep kernels ----------------
// permuted column: n' = ntile*64 + gate*16 + u  (ntile = j>>4, u = j&15)
// K-order: the TIGHT-gated operand goes LAST:
//   Wz1t: k<256 -> W1[k] (x),  k>=256 -> U1[k-256] (h1[s-1], peer-gated)
//   Wz2t: k<512 -> W2[k] (h1), k>=512 -> U2[k-512] (h2[s-1], peer-gated)

__global__ __launch_bounds__(256) void prep_weights(
    const float* __restrict__ W1, const float* __restrict__ U1, const float* __restrict__ b1,
    const float* __restrict__ W2, const float* __restrict__ U2, const float* __restrict__ b2,
    __hip_bfloat16* __restrict__ Wz1t, __hip_bfloat16* __restrict__ Wz2t,
    float* __restrict__ bz1, float* __restrict__ bz2) {
  long idx = (long)blockIdx.x * 256 + threadIdx.x;
  const long n1 = 2048L * K1, n2 = 2048L * K2;
  if (idx < n1) {
    int n = (int)(idx / K1), k = (int)(idx % K1);
    int col = ((n >> 4) & 3) * 512 + (n >> 6) * 16 + (n & 15);
    float v = (k < 256) ? W1[(size_t)k * 2048 + col] : U1[(size_t)(k - 256) * 2048 + col];
    Wz1t[idx] = __float2bfloat16(v);
  } else if (idx < n1 + n2) {
    long r = idx - n1;
    int n = (int)(r / K2), k = (int)(r % K2);
    int col = ((n >> 4) & 3) * 512 + (n >> 6) * 16 + (n & 15);
    float v = (k < 512) ? W2[(size_t)k * 2048 + col] : U2[(size_t)(k - 512) * 2048 + col];
    Wz2t[r] = __float2bfloat16(v);
  } else if (idx < n1 + n2 + 2048) {
    int n = (int)(idx - (n1 + n2));
    bz1[n] = b1[((n >> 4) & 3) * 512 + (n >> 6) * 16 + (n & 15)];
  } else if (idx < n1 + n2 + 4096) {
    int n = (int)(idx - (n1 + n2 + 2048));
    bz2[n] = b2[((n >> 4) & 3) * 512 + (n >> 6) * 16 + (n & 15)];
  }
}

__global__ __launch_bounds__(256) void prep_gather(
    const int* __restrict__ tokens, const float* __restrict__ emb,
    __hip_bfloat16* __restrict__ Xall, float4* __restrict__ zp, int zn) {
  int idx = blockIdx.x * 256 + threadIdx.x;
  if (idx < zn) zp[idx] = make_float4(0.f, 0.f, 0.f, 0.f);   // zero state+flags
  int e  = (idx & 63) * 4;
  int rb = idx >> 6;            // t*512 + b
  int t  = rb >> 9;
  int b  = rb & 511;
  int tok = tokens[b * TSTEPS + t];
  const float4 v = *(const float4*)&emb[(size_t)tok * EDIM + e];
  __hip_bfloat16* o = Xall + (size_t)rb * EDIM + e;
  o[0] = __float2bfloat16(v.x); o[1] = __float2bfloat16(v.y);
  o[2] = __float2bfloat16(v.z); o[3] = __float2bfloat16(v.w);
}

// ---------------- main kernel ----------------
// R15 = R10 (proven 610us; gates/tail/fences/ring byte-identical) + ONE
// delta: NCH 16 -> 20. Rationale: R13/R14 falsified the latency-bound model
// (deeper prefetch / reg transport both regressed); the K-loop cost is LDS
// read traffic serialized against MFMA issue at 1 wave/SIMD. B-fragments for
// chunks < NCH live in registers/AGPRs (zero LDS reads, re-used all 80
// steps); each chunk moved from BsL to breg saves 16KB of LDS reads per step
// per CU. 4 more chunks per role = -64KB/step (-12.5% z2 read traffic).
// VGPR: breg 320 + acc 32 + af/bf 48 + misc ~ 435 < 450 no-spill threshold;
// compiler already AGPR-splits breg (224 arch VGPRs at NCH=16).

__device__ __forceinline__ void gate_wave(const int* flags, int base1, int t1,
                                          int base2, int t2, int lane) {
  const int idx = lane & 31;
  const int* fp = flags + (((lane < 32) ? base1 : base2) + idx) * 4;   // 16B stride
  const int tgt = (lane < 32) ? t1 : t2;
  for (;;) {
    int v = coh_load_i(fp);
    if (__ballot(v >= tgt) == ~0ull) break;
    __builtin_amdgcn_s_sleep(2);
  }
}

template<int K0, int LEN, int STRIDE, bool COH>
__device__ __forceinline__ void run_part(
    const __hip_bfloat16* __restrict__ Asrc, int m0, int w, int lane,
    __hip_bfloat16* __restrict__ ring, const __hip_bfloat16* __restrict__ BsL,
    const bf16x8 (&breg)[NCH][4], const int (&aoff)[2], const int (&boff)[4],
    f32x4 (&acc)[2][4]) {
  auto stage = [&](int kc) {
#pragma unroll
    for (int it = 0; it < 2; ++it) {
      const int gbase = w * 128 + it * 64;
      const int g   = gbase + lane;
      const int row = g >> 2;
      const int gc  = (g & 3) ^ ((row >> 1) & 3);       // XOR swizzle
      __hip_bfloat16* lp = ring + (kc & 7) * 4096 + gbase * 8;
      const __hip_bfloat16* gp = Asrc + (size_t)(m0 + row) * STRIDE + (kc - K0) * 32 + gc * 8;
      if (COH) GLOAD16_H(gp, lp); else GLOAD16_C(gp, lp);
    }
  };
#pragma unroll
  for (int f = 0; f < 6; ++f) stage(K0 + f);            // fill (LEN >= 8 always)

  bf16x8 af[2][2], bf[2][4];
  wait_vm_chunks(5);                                    // chunk K0 resident
#pragma unroll
  for (int mi = 0; mi < 2; ++mi)
    af[0][mi] = *(const bf16x8*)(ring + (K0 & 7) * 4096 + aoff[mi]);
  if (K0 >= NCH)
#pragma unroll
    for (int g = 0; g < 4; ++g)
      bf[0][g] = *(const bf16x8*)(BsL + (K0 - NCH) * 2048 + boff[g]);

#pragma unroll
  for (int i = 0; i < LEN; ++i) {
    const int kc  = K0 + i;
    const int cur = i & 1, nxt = cur ^ 1;
    if (i + 1 < LEN) {
      wait_vm_chunks(LEN - 2 - i < 4 ? LEN - 2 - i : 4);   // chunk kc+1 resident
      const int kn = kc + 1;
#pragma unroll
      for (int mi = 0; mi < 2; ++mi)
        af[nxt][mi] = *(const bf16x8*)(ring + (kn & 7) * 4096 + aoff[mi]);
      if (kn >= NCH) {
#pragma unroll
        for (int g = 0; g < 4; ++g)
          bf[nxt][g] = *(const bf16x8*)(BsL + (kn - NCH) * 2048 + boff[g]);
        wait_lgkm_n(6);                 // frags of kc done; kc+1's 6 in flight
      } else {
        wait_lgkm_n(2);
      }
      if (i + 6 < LEN) stage(kc + 6);   // slot (kc+6)&7: read 2 iters ago -> free
    } else {
      wait_lgkm_n(0);
    }
#pragma unroll
    for (int mi = 0; mi < 2; ++mi)
#pragma unroll
      for (int g = 0; g < 4; ++g)
        acc[mi][g] = __builtin_amdgcn_mfma_f32_16x16x32_bf16(
            af[cur][mi], (kc < NCH ? breg[kc][g] : bf[cur][g]), acc[mi][g], 0, 0, 0);
  }
}

template<bool Z2>
__device__ __forceinline__ void role_loop(const Params& p, char* smem, int tid,
                                          int grp, int ntile) {
  constexpr int K   = Z2 ? K2 : K1;
  constexpr int NC  = K / 32;
  const int lane = tid & 63;
  const int w    = tid >> 6;
  const int q    = lane >> 4;
  const int m16  = lane & 15;
  const int m0   = grp * 128;
  const int n0   = ntile * 64;

  __hip_bfloat16* BsL  = (__hip_bfloat16*)smem;
  __hip_bfloat16* ring = (__hip_bfloat16*)(smem + RING_OFF);
  __hip_bfloat16* epi  = (__hip_bfloat16*)(smem + EPI_OFF);

  const __hip_bfloat16* Bg = (Z2 ? p.Wz2t : p.Wz1t) + (size_t)n0 * K;

  // one-time: B chunks 0..NCH-1 into registers (static indexing only)
  bf16x8 breg[NCH][4];
#pragma unroll
  for (int kc = 0; kc < NCH; ++kc)
#pragma unroll
    for (int g = 0; g < 4; ++g)
      breg[kc][g] = *(const bf16x8*)(Bg + (size_t)(g * 16 + m16) * K + kc * 32 + q * 8);

  // one-time: B chunks NCH..NC-1 into LDS, chunk-major granule-swizzled
  for (int it0 = tid; it0 < (NC - NCH) * 256; it0 += 256) {
    int cid = it0 >> 8, gg = it0 & 255;
    int r = gg >> 2, c8 = gg & 3;
    int sw = c8 ^ ((r >> 1) & 3);
    *(bf16x8*)(BsL + cid * 2048 + r * 32 + sw * 8) =
        *(const bf16x8*)(Bg + (size_t)r * K + (NCH + cid) * 32 + c8 * 8);
  }
  const float* bias = Z2 ? p.bz2 : p.bz1;
  float bz[4];
#pragma unroll
  for (int g = 0; g < 4; ++g) bz[g] = bias[n0 + g * 16 + m16];

  const int swz = (q ^ ((m16 >> 1) & 3)) * 8;
  int aoff[2], boff[4];
#pragma unroll
  for (int mi = 0; mi < 2; ++mi) aoff[mi] = (w * 32 + mi * 16 + m16) * 32 + swz;
#pragma unroll
  for (int g = 0; g < 4; ++g)    boff[g]  = (g * 16 + m16) * 32 + swz;

  float cst[2][4] = {{0.f,0.f,0.f,0.f},{0.f,0.f,0.f,0.f}};
  const int fself = (Z2 ? 128 : 0) + grp * 32 + ntile;
  const int jbase = ntile * 16;
  __syncthreads();

  // pre-loop: z2's slack gate for step 0 (z1 >= 1 -> h1[0] committed)
  if (Z2) {
    if (w == 0) gate_wave(p.flags, grp * 32, 1, grp * 32, 1, lane);
    __syncthreads();
  }

  for (int s = 0; s < TSTEPS; ++s) {
    const int sl = s % D_SLOTS, slp = (s + D_SLOTS - 1) % D_SLOTS;
    const __hip_bfloat16* Aa = Z2
        ? (const __hip_bfloat16*)(p.h1base + (size_t)sl * SLOT_BYTES)    // h1[s]
        : p.Xall + (size_t)s * BATCH * EDIM;                             // x[s]
    const __hip_bfloat16* Ab = Z2
        ? (const __hip_bfloat16*)(p.h2base + (size_t)slp * SLOT_BYTES)   // h2[s-1]
        : (const __hip_bfloat16*)(p.h1base + (size_t)slp * SLOT_BYTES);  // h1[s-1]
    __hip_bfloat16* hout = (__hip_bfloat16*)
        ((Z2 ? p.h2base : p.h1base) + (size_t)sl * SLOT_BYTES);

    f32x4 acc[2][4];
#pragma unroll
    for (int mi = 0; mi < 2; ++mi)
#pragma unroll
      for (int g = 0; g < 4; ++g)
        acc[mi][g] = (f32x4){bz[g], bz[g], bz[g], bz[g]};

    // ---- part A (z2 slack gate already satisfied in previous tail) ----
    if (Z2) run_part<0, 16, 512, true >(Aa, m0, w, lane, ring, BsL, breg, aoff, boff, acc);
    else    run_part<0,  8, 256, false>(Aa, m0, w, lane, ring, BsL, breg, aoff, boff, acc);

    // ---- part B gate (tight peer RAW, hidden behind part A) + fence ----
    if (w == 0) {
      if (Z2) gate_wave(p.flags, 128 + grp * 32, s, 128 + grp * 32, s, lane);
      else    gate_wave(p.flags, grp * 32, s, 128 + grp * 32, s - (D_SLOTS - 1), lane);
      if ((s & 7) == 0) __builtin_amdgcn_fence(__ATOMIC_ACQUIRE, "agent");
    }
    __syncthreads();
    if (Z2) run_part<16, 16, 512, true>(Ab, m0, w, lane, ring, BsL, breg, aoff, boff, acc);
    else    run_part< 8, 16, 512, true>(Ab, m0, w, lane, ring, BsL, breg, aoff, boff, acc);

    // epilogue: gates -> cell state (regs) -> h via LDS transpose
#pragma unroll
    for (int mi = 0; mi < 2; ++mi)
#pragma unroll
      for (int rr = 0; rr < 4; ++rr) {
        const float zi = acc[mi][0][rr], zf = acc[mi][1][rr];
        const float zg = acc[mi][2][rr], zo = acc[mi][3][rr];
        const float cn = sigm(zf) * cst[mi][rr] + sigm(zi) * tanhp(zg);
        cst[mi][rr] = cn;
        epi[(w * 32 + mi * 16 + q * 4 + rr) * EPI_STR + m16] = __float2bfloat16(sigm(zo) * tanhp(cn));
      }
    __syncthreads();
    {
      const int r = tid >> 1, hf = tid & 1;
      bf16x8 hv = *(const bf16x8*)(epi + r * EPI_STR + hf * 8);
      coh_store16(hout + (size_t)(m0 + r) * HDIM + jbase + hf * 8, hv);
    }
    // z2: next step's slack gate polls here -- its vmcnt(0) subsumes the
    // store drain, so flag_store is not delayed. (z1 lead >= 2 in steady
    // state; startup transient only at s=0.)
    if (Z2 && w == 0 && s + 1 < TSTEPS)
      gate_wave(p.flags, grp * 32, s + 2, grp * 32, s + 2, lane);
    WAIT_VM0;                                      // h committed to LLC
    __syncthreads();
    if (tid == 0) flag_store(p.flags + fself * 4, s + 1);
  }
}

__global__ __launch_bounds__(256, 1) void lstm_seq(Params p) {
  extern __shared__ char smem[];
  const int tid = threadIdx.x;
  const bool z2  = ((blockIdx.x & 1) == 0);
  const int grp  = (blockIdx.x >> 1) & 3;
  const int ntile = blockIdx.x >> 3;

  if (z2) role_loop<true>(p, smem, tid, grp, ntile);
  else    role_loop<false>(p, smem, tid, grp, ntile);

  // final FC: block b -> rows {2b, 2b+1}; wait on producing z2 group's flags
  const int lane = tid & 63, w = tid >> 6;
  if (w == 0) {
    const int g2 = blockIdx.x >> 6;
    gate_wave(p.flags, 128 + g2 * 32, TSTEPS, 128 + g2 * 32, TSTEPS, lane);
  }
  __syncthreads();
  if (w < 2) {
    const int row = blockIdx.x * 2 + w;
    const unsigned int* hp = (const unsigned int*)
        (p.h2base + (size_t)((TSTEPS - 1) % D_SLOTS) * SLOT_BYTES) + (size_t)row * (HDIM / 2);
    float sum = 0.f;
#pragma unroll
    for (int cc = 0; cc < 4; ++cc) {
      unsigned int d = coh_load(hp + lane * 4 + cc);
      union { unsigned int ui; float f; } lo, hi;
      lo.ui = d << 16; hi.ui = d & 0xffff0000u;
      sum += lo.f * p.Wfc[(lane * 4 + cc) * 2] + hi.f * p.Wfc[(lane * 4 + cc) * 2 + 1];
    }
#pragma unroll
    for (int o = 32; o > 0; o >>= 1) sum += __shfl_down(sum, o, 64);
    if (lane == 0) p.out[row] = sigm(sum + p.bfc[0]);
  }
}

// ---------------- host launcher ----------------

extern "C" void kernel_launch(void* const* d_in, const int* in_sizes, int n_in,
                              void* d_out, int out_size, void* d_ws, size_t ws_size,
                              hipStream_t stream) {
  const int*   tokens = (const int*)d_in[0];
  const float* emb = (const float*)d_in[1];
  const float* W1  = (const float*)d_in[2];
  const float* U1  = (const float*)d_in[3];
  const float* b1  = (const float*)d_in[4];
  const float* W2  = (const float*)d_in[5];
  const float* U2  = (const float*)d_in[6];
  const float* b2  = (const float*)d_in[7];
  const float* Wfc = (const float*)d_in[8];
  const float* bfc = (const float*)d_in[9];

  char* ws = (char*)d_ws;
  size_t off = 0;
  auto alloc = [&](size_t bytes) {
    char* r = ws + off;
    off += (bytes + 255) & ~(size_t)255;
    return r;
  };
  __hip_bfloat16* Wz1t = (__hip_bfloat16*)alloc(2048UL * K1 * 2);
  __hip_bfloat16* Wz2t = (__hip_bfloat16*)alloc(2048UL * K2 * 2);
  float* bz1 = (float*)alloc(2048 * 4);
  float* bz2 = (float*)alloc(2048 * 4);
  __hip_bfloat16* Xall = (__hip_bfloat16*)alloc((size_t)TSTEPS * BATCH * EDIM * 2);
  // state: 24 h-slots (12 h1 + 12 h2) + flags (4096B), ALL zeroed in prep_gather
  const size_t state_bytes = 24UL * SLOT_BYTES + 4096;   // 12,593,152
  char* state = alloc(state_bytes);

  Params prm;
  prm.h1base = state;
  prm.h2base = state + 12UL * SLOT_BYTES;
  prm.flags  = (int*)(state + 24UL * SLOT_BYTES);

  prep_weights<<<dim3(14352), dim3(256), 0, stream>>>(W1, U1, b1, W2, U2, b2, Wz1t, Wz2t, bz1, bz2);
  prep_gather<<<dim3(10240), dim3(256), 0, stream>>>(tokens, emb, Xall,
                                                     (float4*)state, (int)(state_bytes / 16));

  hipFuncSetAttribute((const void*)lstm_seq,
                      hipFuncAttributeMaxDynamicSharedMemorySize, LDS_BYTES);

  prm.Wz1t = Wz1t; prm.Wz2t = Wz2t; prm.bz1 = bz1; prm.bz2 = bz2;
  prm.Xall = Xall;
  prm.Wfc = Wfc; prm.bfc = bfc;
  prm.out = (float*)d_out;

  lstm_seq<<<dim3(256), dim3(256), LDS_BYTES, stream>>>(prm);
}